// Round 6
// baseline (376.429 us; speedup 1.0000x reference)
//
#include <hip/hip_runtime.h>
#include <hip/hip_cooperative_groups.h>

#define NN 10000
#define EE 160000
#define DD 512
#define CAP 128   // bucket capacity; deg ~ Poisson(16), P(>=128) ~ 0 (writes clamped)

typedef float floatx4 __attribute__((ext_vector_type(4)));
typedef short short8 __attribute__((ext_vector_type(8)));

#define AS3(p) ((__attribute__((address_space(3))) void*)(p))
#define AS1(p) ((const __attribute__((address_space(1))) void*)(p))

static __device__ __forceinline__ unsigned short f2bf(float f) {
    unsigned int u = __float_as_uint(f);
    unsigned int r = (u + 0x7fffu + ((u >> 16) & 1u)) >> 16;
    return (unsigned short)r;
}
// HW packed convert: lo16 = bf16(a), hi16 = bf16(b). RNE, 1 instr (gfx950; no builtin).
static __device__ __forceinline__ unsigned int cvtpk(float a, float b) {
    unsigned int r;
    asm("v_cvt_pk_bf16_f32 %0, %1, %2" : "=v"(r) : "v"(a), "v"(b));
    return r;
}
static __device__ __forceinline__ float bflo(unsigned int u) {
    return __uint_as_float(u << 16);
}
static __device__ __forceinline__ float bfhi(unsigned int u) {
    return __uint_as_float(u & 0xffff0000u);
}

// ---------------- task layout ----------------
#define XB_TASKS 5000
#define WT_TASKS 256
#define ZERO_TASKS 20
#define PREP_TASKS (XB_TASKS + WT_TASKS + ZERO_TASKS)   // 5276
#define GEMM_TASKS 628                                   // 157 row-tiles x 4 col-tiles
#define EDGE_TASKS 625
#define PHASEB_TASKS (GEMM_TASKS + EDGE_TASKS)           // 1253
#define AGG_TASKS (NN * 2)                               // (node, col-half) wave-tasks

// ================= fused cooperative kernel: prep | sync | edge+GEMM | sync | aggregate =================
__global__ __launch_bounds__(256) void k_fused(const float* __restrict__ x,
                                               const float* __restrict__ W,
                                               const int* __restrict__ row,
                                               const int* __restrict__ col,
                                               const float* __restrict__ ew,
                                               unsigned short* __restrict__ xb,
                                               unsigned short* __restrict__ wtb,
                                               unsigned short* __restrict__ hb,
                                               float* __restrict__ deg,
                                               int* __restrict__ cursor,
                                               uint2* __restrict__ erw,
                                               const float* __restrict__ bias,
                                               float* __restrict__ out) {
    __shared__ unsigned short As[64 * 32];    // 4 KB   (phase B)
    __shared__ unsigned short Bs[128 * 32];   // 8 KB   (phase B)
    __shared__ float T[32][33];               // 4.2 KB (phase A)

    const int tid = threadIdx.x;
    const int nb = gridDim.x;
    const int wave = tid >> 6;
    const int lane = tid & 63;

    // ---------------- phase A: x->bf16 | W^T bf16 | zero deg/cursor ----------------
    for (int task = blockIdx.x; task < PREP_TASKS; task += nb) {
        if (task < XB_TASKS) {
            int gid = task * 256 + tid;                      // float4 group of x
            float4 v = *(const float4*)&x[(size_t)gid * 4];
            *(uint2*)&xb[(size_t)gid * 4] = make_uint2(cvtpk(v.x, v.y), cvtpk(v.z, v.w));
        } else if (task < XB_TASKS + WT_TASKS) {
            int idx = task - XB_TASKS;
            int bi = idx & 15;        // k-tile
            int bj = idx >> 4;        // n-tile
            int r0 = tid >> 5;        // 0..7
            int cc = tid & 31;
            #pragma unroll
            for (int k = 0; k < 4; k++) {
                int r = r0 + k * 8;
                T[r][cc] = W[(size_t)(bi * 32 + r) * DD + bj * 32 + cc];
            }
            __syncthreads();
            #pragma unroll
            for (int k = 0; k < 4; k++) {
                int r = r0 + k * 8;
                wtb[(size_t)(bj * 32 + r) * DD + bi * 32 + cc] = f2bf(T[cc][r]);   // wtb[n][k]=W[k][n]
            }
            __syncthreads();          // guard T reuse if a block ever gets 2 WT tasks
        } else {
            // zero deg + cursor (contiguous 81920 B = 20 tasks x 256 thr x 16 B)
            int idx = (task - XB_TASKS - WT_TASKS) * 256 + tid;
            ((uint4*)deg)[idx] = make_uint4(0u, 0u, 0u, 0u);
        }
    }

    __threadfence();
    cooperative_groups::this_grid().sync();

    // ---------------- phase B: GEMM tiles (0..627) + edge pass (628..1252) ----------------
    for (int task = blockIdx.x; task < PHASEB_TASKS; task += nb) {
        if (task >= GEMM_TASKS) {
            // -------- edge pass: deg accum + bucket build (exactly covers EE) --------
            int e = (task - GEMM_TASKS) * 256 + tid;
            int r = row[e];
            int t = col[e];
            float w = ew[e];
            atomicAdd(&deg[t], w);
            int p = atomicAdd(&cursor[t], 1);
            if (p < CAP) erw[t * CAP + p] = make_uint2((unsigned int)r, __float_as_uint(w));
        } else {
            // -------- GEMM: hb = bf16(xb @ wtb^T), 64x128 tile (R1-measured body) --------
            const int bid = task;
            const int bm = (bid >> 2) * 64;
            const int bn = (bid & 3) * 128;
            const int wm = (wave >> 1) * 32;   // 0 / 32
            const int wn = (wave & 1) * 64;    // 0 / 64
            const int fm = lane & 15;
            const int kb = (lane >> 4) * 8;
            const int srow = lane >> 2;        // 0..15 within a 16-row chunk
            const int scol = (lane & 3) * 8;   // 0,8,16,24

            floatx4 acc[2][4];
            #pragma unroll
            for (int i = 0; i < 2; i++)
                #pragma unroll
                for (int j = 0; j < 4; j++)
                    acc[i][j] = (floatx4){0.f, 0.f, 0.f, 0.f};

            int gr = bm + wave * 16 + srow; if (gr > NN - 1) gr = NN - 1;   // clamp (stores guarded)

            for (int k0 = 0; k0 < DD; k0 += 32) {
                __builtin_amdgcn_global_load_lds(AS1(xb + (size_t)gr * DD + k0 + scol),
                                                 AS3(&As[wave * 512]), 16, 0, 0);
                #pragma unroll
                for (int cc = 0; cc < 2; cc++) {
                    int c = wave + cc * 4;
                    int nr = bn + c * 16 + srow;
                    __builtin_amdgcn_global_load_lds(AS1(wtb + (size_t)nr * DD + k0 + scol),
                                                     AS3(&Bs[c * 512]), 16, 0, 0);
                }
                __syncthreads();

                short8 af[2], bfr[4];
                #pragma unroll
                for (int mi = 0; mi < 2; mi++)
                    af[mi] = *(const short8*)&As[(wm + mi * 16 + fm) * 32 + kb];
                #pragma unroll
                for (int ni = 0; ni < 4; ni++)
                    bfr[ni] = *(const short8*)&Bs[(wn + ni * 16 + fm) * 32 + kb];

                #pragma unroll
                for (int mi = 0; mi < 2; mi++)
                    #pragma unroll
                    for (int ni = 0; ni < 4; ni++)
                        acc[mi][ni] = __builtin_amdgcn_mfma_f32_16x16x32_bf16(af[mi], bfr[ni], acc[mi][ni], 0, 0, 0);

                __syncthreads();
            }

            #pragma unroll
            for (int mi = 0; mi < 2; mi++) {
                #pragma unroll
                for (int ni = 0; ni < 4; ni++) {
                    int colg = bn + wn + ni * 16 + (lane & 15);
                    int rbase = bm + wm + mi * 16 + (lane >> 4) * 4;
                    #pragma unroll
                    for (int j = 0; j < 4; j++) {
                        int rg = rbase + j;
                        if (rg < NN) hb[(size_t)rg * DD + colg] = f2bf(acc[mi][ni][j]);
                    }
                }
            }
        }
    }

    __threadfence();
    cooperative_groups::this_grid().sync();

    // ---------------- phase C: aggregate, barrier-free (one wave per (node, col-half)) ----------------
    // Bucket entries live in registers (2 per lane), broadcast via __shfl.
    // dinv[row] folded at entry-load time; padded entries get w=0, row=self (safe address).
    const int wgid = blockIdx.x * 4 + wave;
    const int wstride = nb * 4;
    for (int t = wgid; t < AGG_TASKS; t += wstride) {
        const int i = t >> 1;                       // node
        const int c = (t & 1) * 256 + lane * 4;     // bf16 col index, 4 cols/lane
        int cnt = cursor[i];
        if (cnt > CAP) cnt = CAP;
        const uint2* bkt = erw + (size_t)i * CAP;

        uint2 e0 = make_uint2((unsigned int)i, 0u);
        uint2 e1 = make_uint2((unsigned int)i, 0u);
        if (lane < cnt)      e0 = bkt[lane];
        if (lane + 64 < cnt) e1 = bkt[lane + 64];
        float wt0 = (lane < cnt)      ? __uint_as_float(e0.y) * rsqrtf(deg[e0.x] + 1.0f) : 0.0f;
        float wt1 = (lane + 64 < cnt) ? __uint_as_float(e1.y) * rsqrtf(deg[e1.x] + 1.0f) : 0.0f;
        int rb0 = (int)e0.x << 9;                   // row * DD
        int rb1 = (int)e1.x << 9;

        float dvv = rsqrtf(deg[i] + 1.0f);
        uint2 hv = *(const uint2*)&hb[(size_t)i * DD + c];
        float4 bv = *(const float4*)&bias[c];

        float a0 = 0.f, a1 = 0.f, a2 = 0.f, a3 = 0.f;
        int cr = (cnt + 7) & ~7;
        for (int j = 0; j < cr; j += 8) {           // j blocks of 8 never straddle the 64 boundary
            int rbs   = (j < 64) ? rb0 : rb1;
            float wss = (j < 64) ? wt0 : wt1;
            int base = j & 63;
            #pragma unroll
            for (int u = 0; u < 8; u++) {
                int rbase = __shfl(rbs, base + u, 64);
                float wq  = __shfl(wss, base + u, 64);
                uint2 p = *(const uint2*)&hb[rbase + c];
                a0 += bflo(p.x) * wq; a1 += bfhi(p.x) * wq;
                a2 += bflo(p.y) * wq; a3 += bfhi(p.y) * wq;
            }
        }

        float4 o;
        o.x = (a0 + bflo(hv.x) * dvv) * dvv + bv.x;
        o.y = (a1 + bfhi(hv.x) * dvv) * dvv + bv.y;
        o.z = (a2 + bflo(hv.y) * dvv) * dvv + bv.z;
        o.w = (a3 + bfhi(hv.y) * dvv) * dvv + bv.w;
        *(float4*)&out[(size_t)i * DD + c] = o;
    }
}

// ================= fallback (non-cooperative) path: R5's 3-kernel chain =================

__global__ __launch_bounds__(256) void k_prep_xw(const float* __restrict__ x,
                                                 const float* __restrict__ W,
                                                 unsigned short* __restrict__ xb,
                                                 unsigned short* __restrict__ wtb,
                                                 uint4* __restrict__ zbase) {
    const int b = blockIdx.x;
    const int tid = threadIdx.x;
    if (b < XB_TASKS) {
        int gid = b * 256 + tid;
        float4 v = *(const float4*)&x[(size_t)gid * 4];
        *(uint2*)&xb[(size_t)gid * 4] = make_uint2(cvtpk(v.x, v.y), cvtpk(v.z, v.w));
    } else if (b < XB_TASKS + WT_TASKS) {
        __shared__ float T[32][33];
        int idx = b - XB_TASKS;
        int bi = idx & 15, bj = idx >> 4;
        int r0 = tid >> 5, cc = tid & 31;
        #pragma unroll
        for (int k = 0; k < 4; k++) {
            int r = r0 + k * 8;
            T[r][cc] = W[(size_t)(bi * 32 + r) * DD + bj * 32 + cc];
        }
        __syncthreads();
        #pragma unroll
        for (int k = 0; k < 4; k++) {
            int r = r0 + k * 8;
            wtb[(size_t)(bj * 32 + r) * DD + bi * 32 + cc] = f2bf(T[cc][r]);
        }
    } else {
        int idx = (b - XB_TASKS - WT_TASKS) * 256 + tid;
        zbase[idx] = make_uint4(0u, 0u, 0u, 0u);
    }
}

__global__ __launch_bounds__(256) void k_gemm_edge(const unsigned short* __restrict__ xb,
                                                   const unsigned short* __restrict__ wtb,
                                                   unsigned short* __restrict__ hb,
                                                   const int* __restrict__ row,
                                                   const int* __restrict__ col,
                                                   const float* __restrict__ ew,
                                                   float* __restrict__ deg,
                                                   int* __restrict__ cursor,
                                                   uint2* __restrict__ erw) {
    __shared__ unsigned short As[64 * 32];
    __shared__ unsigned short Bs[128 * 32];
    const int tid = threadIdx.x;

    if (blockIdx.x < EDGE_TASKS) {
        int e = blockIdx.x * 256 + tid;
        int r = row[e];
        int t = col[e];
        float w = ew[e];
        atomicAdd(&deg[t], w);
        int p = atomicAdd(&cursor[t], 1);
        if (p < CAP) erw[t * CAP + p] = make_uint2((unsigned int)r, __float_as_uint(w));
        return;
    }

    const int bid = blockIdx.x - EDGE_TASKS;
    const int wave = tid >> 6;
    const int lane = tid & 63;
    const int bm = (bid >> 2) * 64;
    const int bn = (bid & 3) * 128;
    const int wm = (wave >> 1) * 32;
    const int wn = (wave & 1) * 64;
    const int fm = lane & 15;
    const int kb = (lane >> 4) * 8;

    floatx4 acc[2][4];
    #pragma unroll
    for (int i = 0; i < 2; i++)
        #pragma unroll
        for (int j = 0; j < 4; j++)
            acc[i][j] = (floatx4){0.f, 0.f, 0.f, 0.f};

    const int srow = lane >> 2;
    const int scol = (lane & 3) * 8;

    for (int k0 = 0; k0 < DD; k0 += 32) {
        {
            int r = wave * 16 + srow;
            int gr = bm + r; if (gr > NN - 1) gr = NN - 1;
            __builtin_amdgcn_global_load_lds(AS1(xb + (size_t)gr * DD + k0 + scol),
                                             AS3(&As[wave * 512]), 16, 0, 0);
        }
        #pragma unroll
        for (int cc = 0; cc < 2; cc++) {
            int c = wave + cc * 4;
            int nr = bn + c * 16 + srow;
            __builtin_amdgcn_global_load_lds(AS1(wtb + (size_t)nr * DD + k0 + scol),
                                             AS3(&Bs[c * 512]), 16, 0, 0);
        }
        __syncthreads();

        short8 af[2], bfr[4];
        #pragma unroll
        for (int mi = 0; mi < 2; mi++)
            af[mi] = *(const short8*)&As[(wm + mi * 16 + fm) * 32 + kb];
        #pragma unroll
        for (int ni = 0; ni < 4; ni++)
            bfr[ni] = *(const short8*)&Bs[(wn + ni * 16 + fm) * 32 + kb];

        #pragma unroll
        for (int mi = 0; mi < 2; mi++)
            #pragma unroll
            for (int ni = 0; ni < 4; ni++)
                acc[mi][ni] = __builtin_amdgcn_mfma_f32_16x16x32_bf16(af[mi], bfr[ni], acc[mi][ni], 0, 0, 0);

        __syncthreads();
    }

    #pragma unroll
    for (int mi = 0; mi < 2; mi++) {
        #pragma unroll
        for (int ni = 0; ni < 4; ni++) {
            int colg = bn + wn + ni * 16 + (lane & 15);
            int rbase = bm + wm + mi * 16 + (lane >> 4) * 4;
            #pragma unroll
            for (int j = 0; j < 4; j++) {
                int rg = rbase + j;
                if (rg < NN) hb[(size_t)rg * DD + colg] = f2bf(acc[mi][ni][j]);
            }
        }
    }
}

#define EDGE_FMA(P, W) a0 += bflo(P) * W; a1 += bfhi(P) * W;

__global__ __launch_bounds__(128, 8) void k_aggregate(const int* __restrict__ cursor,
                                                      const uint2* __restrict__ erw,
                                                      const unsigned short* __restrict__ hb,
                                                      const float* __restrict__ deg,
                                                      const float* __restrict__ bias,
                                                      float* __restrict__ out) {
    const int h = threadIdx.x >> 6;
    const int t = threadIdx.x & 63;
    const int bid = blockIdx.x;
    const int q = bid & 3;
    const int i = (bid >> 2) * 2 + h;
    const int c = q * 128 + t * 2;

    __shared__ int   s_r[2][CAP];
    __shared__ float s_w[2][CAP];

    int cnt = cursor[i];
    if (cnt > CAP) cnt = CAP;
    const uint2* bkt = erw + (size_t)i * CAP;
    if (t < cnt) {
        uint2 p = bkt[t];
        int r = (int)p.x;
        s_r[h][t] = r << 9;
        s_w[h][t] = __uint_as_float(p.y) * rsqrtf(deg[r] + 1.0f);
    }
    if (t + 64 < cnt) {
        uint2 p = bkt[t + 64];
        int r = (int)p.x;
        s_r[h][t + 64] = r << 9;
        s_w[h][t + 64] = __uint_as_float(p.y) * rsqrtf(deg[r] + 1.0f);
    }

    float dv = rsqrtf(deg[i] + 1.0f);
    unsigned int hv = *(const unsigned int*)&hb[(size_t)i * DD + c];
    float2 bv = *(const float2*)&bias[c];

    __syncthreads();

    float a0 = 0.f, a1 = 0.f;
    int j = 0;
    for (; j + 8 <= cnt; j += 8) {
        unsigned int p0 = *(const unsigned int*)&hb[s_r[h][j    ] + c];
        unsigned int p1 = *(const unsigned int*)&hb[s_r[h][j + 1] + c];
        unsigned int p2 = *(const unsigned int*)&hb[s_r[h][j + 2] + c];
        unsigned int p3 = *(const unsigned int*)&hb[s_r[h][j + 3] + c];
        unsigned int p4 = *(const unsigned int*)&hb[s_r[h][j + 4] + c];
        unsigned int p5 = *(const unsigned int*)&hb[s_r[h][j + 5] + c];
        unsigned int p6 = *(const unsigned int*)&hb[s_r[h][j + 6] + c];
        unsigned int p7 = *(const unsigned int*)&hb[s_r[h][j + 7] + c];
        float w0 = s_w[h][j],     w1 = s_w[h][j + 1], w2 = s_w[h][j + 2], w3 = s_w[h][j + 3];
        float w4 = s_w[h][j + 4], w5 = s_w[h][j + 5], w6 = s_w[h][j + 6], w7 = s_w[h][j + 7];
        EDGE_FMA(p0, w0) EDGE_FMA(p1, w1) EDGE_FMA(p2, w2) EDGE_FMA(p3, w3)
        EDGE_FMA(p4, w4) EDGE_FMA(p5, w5) EDGE_FMA(p6, w6) EDGE_FMA(p7, w7)
    }
    for (; j < cnt; j++) {
        unsigned int p0 = *(const unsigned int*)&hb[s_r[h][j] + c];
        float w0 = s_w[h][j];
        EDGE_FMA(p0, w0)
    }

    float2 o;
    o.x = (a0 + bflo(hv) * dv) * dv + bv.x;
    o.y = (a1 + bfhi(hv) * dv) * dv + bv.y;
    *(float2*)&out[(size_t)i * DD + c] = o;
}

// ================= host =================

extern "C" void kernel_launch(void* const* d_in, const int* in_sizes, int n_in,
                              void* d_out, int out_size, void* d_ws, size_t ws_size,
                              hipStream_t stream) {
    const float* x  = (const float*)d_in[0];
    const int*   ei = (const int*)d_in[1];
    const float* ea = (const float*)d_in[2];
    const float* W  = (const float*)d_in[3];
    const float* b  = (const float*)d_in[4];
    float* out = (float*)d_out;

    char* ws = (char*)d_ws;
    unsigned short* hb   = (unsigned short*)ws;                 // 10,240,000 B
    unsigned short* xb   = (unsigned short*)(ws + 10240000);    // 10,240,000 B
    unsigned short* wtb  = (unsigned short*)(ws + 20480000);    // 524,288 B
    float* deg    = (float*)(ws + 21004288);                    // 40,960 B
    int*   cursor = (int*)  (ws + 21045248);                    // 40,960 B
    uint2* erw    = (uint2*)(ws + 21086208);                    // 10,240,000 B

    const int* row = ei;
    const int* col = ei + EE;

    // grid = exact co-resident capacity (the validator cooperative launch uses)
    static int coop_grid = 0;
    if (coop_grid == 0) {
        int per_cu = 0;
        hipOccupancyMaxActiveBlocksPerMultiprocessor(&per_cu, k_fused, 256, 0);
        if (per_cu < 1) per_cu = 1;
        if (per_cu > 8) per_cu = 8;
        coop_grid = per_cu * 256;   // 256 CUs on MI355X
    }

    void* args[] = { (void*)&x, (void*)&W, (void*)&row, (void*)&col, (void*)&ea,
                     (void*)&xb, (void*)&wtb, (void*)&hb,
                     (void*)&deg, (void*)&cursor, (void*)&erw,
                     (void*)&b, (void*)&out };

    hipError_t err = hipLaunchCooperativeKernel((const void*)k_fused,
                                                dim3(coop_grid), dim3(256),
                                                args, 0, stream);
    if (err != hipSuccess) {
        // fallback: R5's 3-kernel chain
        k_prep_xw<<<XB_TASKS + WT_TASKS + ZERO_TASKS, 256, 0, stream>>>(x, W, xb, wtb, (uint4*)deg);
        k_gemm_edge<<<EDGE_TASKS + GEMM_TASKS, 256, 0, stream>>>(xb, wtb, hb, row, col, ea,
                                                                 deg, cursor, erw);
        k_aggregate<<<NN * 2, 128, 0, stream>>>(cursor, erw, hb, deg, b, out);
    }
}

// Round 7
// 130.803 us; speedup vs baseline: 2.8778x; 2.8778x over previous
//
#include <hip/hip_runtime.h>

#define NN 10000
#define EE 160000
#define DD 512
#define CAP 128   // bucket capacity; deg ~ Poisson(16), P(>=128) ~ 0 (writes clamped)

typedef float floatx4 __attribute__((ext_vector_type(4)));
typedef short short8 __attribute__((ext_vector_type(8)));

#define AS3(p) ((__attribute__((address_space(3))) void*)(p))
#define AS1(p) ((const __attribute__((address_space(1))) void*)(p))

static __device__ __forceinline__ unsigned short f2bf(float f) {
    unsigned int u = __float_as_uint(f);
    unsigned int r = (u + 0x7fffu + ((u >> 16) & 1u)) >> 16;
    return (unsigned short)r;
}
// HW packed convert: lo16 = bf16(a), hi16 = bf16(b). RNE, 1 instr (gfx950; no builtin).
static __device__ __forceinline__ unsigned int cvtpk(float a, float b) {
    unsigned int r;
    asm("v_cvt_pk_bf16_f32 %0, %1, %2" : "=v"(r) : "v"(a), "v"(b));
    return r;
}
static __device__ __forceinline__ float bflo(unsigned int u) {
    return __uint_as_float(u << 16);
}
static __device__ __forceinline__ float bfhi(unsigned int u) {
    return __uint_as_float(u & 0xffff0000u);
}

// ---------------- prep: x->bf16 | W->W^T bf16 (LDS-tiled) ----------------

#define XB_BLOCKS 5000
#define WT_BLOCKS 256
#define EDGE_BLOCKS 625
#define GM_BLOCKS (157 * 4)   // 64-row tiles x 4 col-tiles of 128

__global__ __launch_bounds__(256) void k_prep_xw(const float* __restrict__ x,
                                                 const float* __restrict__ W,
                                                 unsigned short* __restrict__ xb,
                                                 unsigned short* __restrict__ wtb) {
    const int b = blockIdx.x;
    const int tid = threadIdx.x;
    if (b < XB_BLOCKS) {
        int gid = b * 256 + tid;                     // float4 group of x
        float4 v = *(const float4*)&x[(size_t)gid * 4];
        *(uint2*)&xb[(size_t)gid * 4] = make_uint2(cvtpk(v.x, v.y), cvtpk(v.z, v.w));
    } else {
        __shared__ float T[32][33];
        int idx = b - XB_BLOCKS;
        int bi = idx & 15;        // k-tile
        int bj = idx >> 4;        // n-tile
        int r0 = tid >> 5;        // 0..7
        int cc = tid & 31;
        #pragma unroll
        for (int k = 0; k < 4; k++) {
            int r = r0 + k * 8;
            T[r][cc] = W[(size_t)(bi * 32 + r) * DD + bj * 32 + cc];
        }
        __syncthreads();
        #pragma unroll
        for (int k = 0; k < 4; k++) {
            int r = r0 + k * 8;
            wtb[(size_t)(bj * 32 + r) * DD + bi * 32 + cc] = f2bf(T[cc][r]);   // wtb[n][k]=W[k][n]
        }
    }
}

// ---------------- fused: edge bucket/deg build (625 blocks) + MFMA GEMM (628 blocks) ----------------
// R1-exact GEMM: single-buffer LDS, A from xb bf16 via async global_load_lds.
// GEMM has no dependency on deg -> latency-bound edge atomics overlap with MFMA blocks.

__global__ __launch_bounds__(256) void k_gemm_edge(const unsigned short* __restrict__ xb,
                                                   const unsigned short* __restrict__ wtb,
                                                   unsigned short* __restrict__ hb,
                                                   const int* __restrict__ row,
                                                   const int* __restrict__ col,
                                                   const float* __restrict__ ew,
                                                   float* __restrict__ deg,
                                                   int* __restrict__ cursor,
                                                   uint2* __restrict__ erw) {
    __shared__ unsigned short As[64 * 32];    // 4 KB
    __shared__ unsigned short Bs[128 * 32];   // 8 KB

    const int tid = threadIdx.x;

    if (blockIdx.x < EDGE_BLOCKS) {
        // -------- edge pass: deg accum + bucket build --------
        int e = blockIdx.x * 256 + tid;        // exactly covers EE
        int r = row[e];
        int t = col[e];
        float w = ew[e];
        atomicAdd(&deg[t], w);
        int p = atomicAdd(&cursor[t], 1);
        if (p < CAP) erw[t * CAP + p] = make_uint2((unsigned int)r, __float_as_uint(w));
        return;
    }

    // -------- GEMM: hb = bf16(xb @ wtb^T), 64x128 tile --------
    const int bid = blockIdx.x - EDGE_BLOCKS;
    const int wave = tid >> 6;
    const int lane = tid & 63;

    const int bm = (bid >> 2) * 64;
    const int bn = (bid & 3) * 128;

    const int wm = (wave >> 1) * 32;   // 0 / 32
    const int wn = (wave & 1) * 64;    // 0 / 64

    const int fm = lane & 15;
    const int kb = (lane >> 4) * 8;

    floatx4 acc[2][4];
    #pragma unroll
    for (int i = 0; i < 2; i++)
        #pragma unroll
        for (int j = 0; j < 4; j++)
            acc[i][j] = (floatx4){0.f, 0.f, 0.f, 0.f};

    const int srow = lane >> 2;          // 0..15 within a 16-row chunk
    const int scol = (lane & 3) * 8;     // 0,8,16,24

    for (int k0 = 0; k0 < DD; k0 += 32) {
        // A: 64 rows, one chunk per wave
        {
            int r = wave * 16 + srow;
            int gr = bm + r; if (gr > NN - 1) gr = NN - 1;   // clamp (stores guarded)
            __builtin_amdgcn_global_load_lds(AS1(xb + (size_t)gr * DD + k0 + scol),
                                             AS3(&As[wave * 512]), 16, 0, 0);
        }
        // B: 128 rows, two chunks per wave
        #pragma unroll
        for (int cc = 0; cc < 2; cc++) {
            int c = wave + cc * 4;
            int nr = bn + c * 16 + srow;
            __builtin_amdgcn_global_load_lds(AS1(wtb + (size_t)nr * DD + k0 + scol),
                                             AS3(&Bs[c * 512]), 16, 0, 0);
        }
        __syncthreads();

        short8 af[2], bfr[4];
        #pragma unroll
        for (int mi = 0; mi < 2; mi++)
            af[mi] = *(const short8*)&As[(wm + mi * 16 + fm) * 32 + kb];
        #pragma unroll
        for (int ni = 0; ni < 4; ni++)
            bfr[ni] = *(const short8*)&Bs[(wn + ni * 16 + fm) * 32 + kb];

        #pragma unroll
        for (int mi = 0; mi < 2; mi++)
            #pragma unroll
            for (int ni = 0; ni < 4; ni++)
                acc[mi][ni] = __builtin_amdgcn_mfma_f32_16x16x32_bf16(af[mi], bfr[ni], acc[mi][ni], 0, 0, 0);

        __syncthreads();
    }

    #pragma unroll
    for (int mi = 0; mi < 2; mi++) {
        #pragma unroll
        for (int ni = 0; ni < 4; ni++) {
            int colg = bn + wn + ni * 16 + (lane & 15);
            int rbase = bm + wm + mi * 16 + (lane >> 4) * 4;
            #pragma unroll
            for (int j = 0; j < 4; j++) {
                int rg = rbase + j;
                if (rg < NN) hb[(size_t)rg * DD + colg] = f2bf(acc[mi][ni][j]);
            }
        }
    }
}

// ---------------- aggregate: column-half split + SOFTWARE-PIPELINED gathers ----------------
// Block bid (128 thr = 2 waves): half = bid&1, wave h handles node (bid>>1)*2 + h,
// columns [half*256, half*256+256), 4 bf16 cols/lane (uint2 gathers, 512 B/row/wave).
// Inner loop register-double-buffers batches of 8 gathers: batch j+1 is issued before
// batch j is consumed -> 2x memory-level parallelism, half the exposed-latency stalls.
// dinv[row] folded at bucket-stage time; hb holds raw h.

__global__ __launch_bounds__(128, 8) void k_aggregate(const int* __restrict__ cursor,
                                                      const uint2* __restrict__ erw,
                                                      const unsigned short* __restrict__ hb,
                                                      const float* __restrict__ deg,
                                                      const float* __restrict__ bias,
                                                      float* __restrict__ out) {
    const int h = threadIdx.x >> 6;
    const int t = threadIdx.x & 63;
    const int bid = blockIdx.x;                // 0..9999
    const int half = bid & 1;
    const int i = (bid >> 1) * 2 + h;          // node
    const int c = half * 256 + t * 4;          // bf16 col index, 4 cols/lane

    __shared__ int   s_r[2][CAP];              // precomputed row*DD element base
    __shared__ float s_w[2][CAP];

    int cnt = cursor[i];
    if (cnt > CAP) cnt = CAP;
    const uint2* bkt = erw + (size_t)i * CAP;
    // stage bucket as uint4 (2 entries per load)
    if (2 * t < cnt) {
        uint4 p = *(const uint4*)&bkt[2 * t];
        int r0 = (int)p.x, r1 = (int)p.z;
        s_r[h][2 * t] = r0 << 9;
        s_w[h][2 * t] = __uint_as_float(p.y) * rsqrtf(deg[r0] + 1.0f);
        if (2 * t + 1 < cnt) {
            s_r[h][2 * t + 1] = r1 << 9;
            s_w[h][2 * t + 1] = __uint_as_float(p.w) * rsqrtf(deg[r1] + 1.0f);
        }
    }

    // hoist self-row + bias
    float dv = rsqrtf(deg[i] + 1.0f);
    uint2 hv = *(const uint2*)&hb[(size_t)i * DD + c];
    float4 bv = *(const float4*)&bias[c];

    __syncthreads();

    float a0 = 0.f, a1 = 0.f, a2 = 0.f, a3 = 0.f;

    const int nfull = cnt & ~7;
    if (nfull >= 8) {
        // prologue: issue batch 0
        uint2 c0 = *(const uint2*)&hb[s_r[h][0] + c];
        uint2 c1 = *(const uint2*)&hb[s_r[h][1] + c];
        uint2 c2 = *(const uint2*)&hb[s_r[h][2] + c];
        uint2 c3 = *(const uint2*)&hb[s_r[h][3] + c];
        uint2 c4 = *(const uint2*)&hb[s_r[h][4] + c];
        uint2 c5 = *(const uint2*)&hb[s_r[h][5] + c];
        uint2 c6 = *(const uint2*)&hb[s_r[h][6] + c];
        uint2 c7 = *(const uint2*)&hb[s_r[h][7] + c];
        int j = 8;
        for (; j <= nfull - 8; j += 8) {
            // issue batch j while batch j-8 is still in flight / being consumed
            uint2 n0 = *(const uint2*)&hb[s_r[h][j    ] + c];
            uint2 n1 = *(const uint2*)&hb[s_r[h][j + 1] + c];
            uint2 n2 = *(const uint2*)&hb[s_r[h][j + 2] + c];
            uint2 n3 = *(const uint2*)&hb[s_r[h][j + 3] + c];
            uint2 n4 = *(const uint2*)&hb[s_r[h][j + 4] + c];
            uint2 n5 = *(const uint2*)&hb[s_r[h][j + 5] + c];
            uint2 n6 = *(const uint2*)&hb[s_r[h][j + 6] + c];
            uint2 n7 = *(const uint2*)&hb[s_r[h][j + 7] + c];
            float w0 = s_w[h][j - 8], w1 = s_w[h][j - 7], w2 = s_w[h][j - 6], w3 = s_w[h][j - 5];
            float w4 = s_w[h][j - 4], w5 = s_w[h][j - 3], w6 = s_w[h][j - 2], w7 = s_w[h][j - 1];
            a0 += bflo(c0.x) * w0; a1 += bfhi(c0.x) * w0; a2 += bflo(c0.y) * w0; a3 += bfhi(c0.y) * w0;
            a0 += bflo(c1.x) * w1; a1 += bfhi(c1.x) * w1; a2 += bflo(c1.y) * w1; a3 += bfhi(c1.y) * w1;
            a0 += bflo(c2.x) * w2; a1 += bfhi(c2.x) * w2; a2 += bflo(c2.y) * w2; a3 += bfhi(c2.y) * w2;
            a0 += bflo(c3.x) * w3; a1 += bfhi(c3.x) * w3; a2 += bflo(c3.y) * w3; a3 += bfhi(c3.y) * w3;
            a0 += bflo(c4.x) * w4; a1 += bfhi(c4.x) * w4; a2 += bflo(c4.y) * w4; a3 += bfhi(c4.y) * w4;
            a0 += bflo(c5.x) * w5; a1 += bfhi(c5.x) * w5; a2 += bflo(c5.y) * w5; a3 += bfhi(c5.y) * w5;
            a0 += bflo(c6.x) * w6; a1 += bfhi(c6.x) * w6; a2 += bflo(c6.y) * w6; a3 += bfhi(c6.y) * w6;
            a0 += bflo(c7.x) * w7; a1 += bfhi(c7.x) * w7; a2 += bflo(c7.y) * w7; a3 += bfhi(c7.y) * w7;
            c0 = n0; c1 = n1; c2 = n2; c3 = n3; c4 = n4; c5 = n5; c6 = n6; c7 = n7;
        }
        // drain last full batch
        {
            float w0 = s_w[h][j - 8], w1 = s_w[h][j - 7], w2 = s_w[h][j - 6], w3 = s_w[h][j - 5];
            float w4 = s_w[h][j - 4], w5 = s_w[h][j - 3], w6 = s_w[h][j - 2], w7 = s_w[h][j - 1];
            a0 += bflo(c0.x) * w0; a1 += bfhi(c0.x) * w0; a2 += bflo(c0.y) * w0; a3 += bfhi(c0.y) * w0;
            a0 += bflo(c1.x) * w1; a1 += bfhi(c1.x) * w1; a2 += bflo(c1.y) * w1; a3 += bfhi(c1.y) * w1;
            a0 += bflo(c2.x) * w2; a1 += bfhi(c2.x) * w2; a2 += bflo(c2.y) * w2; a3 += bfhi(c2.y) * w2;
            a0 += bflo(c3.x) * w3; a1 += bfhi(c3.x) * w3; a2 += bflo(c3.y) * w3; a3 += bfhi(c3.y) * w3;
            a0 += bflo(c4.x) * w4; a1 += bfhi(c4.x) * w4; a2 += bflo(c4.y) * w4; a3 += bfhi(c4.y) * w4;
            a0 += bflo(c5.x) * w5; a1 += bfhi(c5.x) * w5; a2 += bflo(c5.y) * w5; a3 += bfhi(c5.y) * w5;
            a0 += bflo(c6.x) * w6; a1 += bfhi(c6.x) * w6; a2 += bflo(c6.y) * w6; a3 += bfhi(c6.y) * w6;
            a0 += bflo(c7.x) * w7; a1 += bfhi(c7.x) * w7; a2 += bflo(c7.y) * w7; a3 += bfhi(c7.y) * w7;
        }
    }
    for (int j = nfull; j < cnt; j++) {
        uint2 p0 = *(const uint2*)&hb[s_r[h][j] + c];
        float w0 = s_w[h][j];
        a0 += bflo(p0.x) * w0; a1 += bfhi(p0.x) * w0;
        a2 += bflo(p0.y) * w0; a3 += bfhi(p0.y) * w0;
    }

    float2 o0, o1;
    o0.x = (a0 + bflo(hv.x) * dv) * dv + bv.x;
    o0.y = (a1 + bfhi(hv.x) * dv) * dv + bv.y;
    o1.x = (a2 + bflo(hv.y) * dv) * dv + bv.z;
    o1.y = (a3 + bfhi(hv.y) * dv) * dv + bv.w;
    *(float2*)&out[(size_t)i * DD + c] = o0;
    *(float2*)&out[(size_t)i * DD + c + 2] = o1;
}

extern "C" void kernel_launch(void* const* d_in, const int* in_sizes, int n_in,
                              void* d_out, int out_size, void* d_ws, size_t ws_size,
                              hipStream_t stream) {
    const float* x  = (const float*)d_in[0];
    const int*   ei = (const int*)d_in[1];
    const float* ea = (const float*)d_in[2];
    const float* W  = (const float*)d_in[3];
    const float* b  = (const float*)d_in[4];
    float* out = (float*)d_out;

    char* ws = (char*)d_ws;
    unsigned short* hb   = (unsigned short*)ws;                 // 10,240,000 B
    unsigned short* xb   = (unsigned short*)(ws + 10240000);    // 10,240,000 B
    unsigned short* wtb  = (unsigned short*)(ws + 20480000);    // 524,288 B
    float* deg    = (float*)(ws + 21004288);                    // 40,960 B
    int*   cursor = (int*)  (ws + 21045248);                    // 40,960 B
    uint2* erw    = (uint2*)(ws + 21086208);                    // 10,240,000 B

    const int* row = ei;
    const int* col = ei + EE;

    hipMemsetAsync(deg, 0, 81920, stream);   // deg + cursor (contiguous)

    k_prep_xw<<<XB_BLOCKS + WT_BLOCKS, 256, 0, stream>>>(x, W, xb, wtb);

    k_gemm_edge<<<EDGE_BLOCKS + GM_BLOCKS, 256, 0, stream>>>(xb, wtb, hb, row, col, ea,
                                                             deg, cursor, erw);

    k_aggregate<<<NN, 128, 0, stream>>>(cursor, erw, hb, deg, b, out);
}